// Round 2
// baseline (3779.171 us; speedup 1.0000x reference)
//
#include <hip/hip_runtime.h>

typedef __bf16 bf16x8 __attribute__((ext_vector_type(8)));
typedef float f32x4 __attribute__((ext_vector_type(4)));

__device__ __forceinline__ float sigmoidf_fast(float x) {
  return 1.f / (1.f + __expf(-x));
}
__device__ __forceinline__ float tanhf_fast(float x) {
  float e = __expf(2.f * x);
  return 1.f - 2.f / (e + 1.f);
}
__device__ __forceinline__ unsigned pack_bf16x2(float a, float b) {
  unsigned short ua = __builtin_bit_cast(unsigned short, (__bf16)a);
  unsigned short ub = __builtin_bit_cast(unsigned short, (__bf16)b);
  return (unsigned)ua | ((unsigned)ub << 16);
}

// Wt[tap][oc][ci] = (bf16)W[oc][ci][tap], tap = ky*3+kx  (k-contiguous A-fragments)
__global__ void transpose_w_kernel(const float* __restrict__ Wsrc,
                                   __bf16* __restrict__ Wt, int C4, int C2) {
  int idx = blockIdx.x * 256 + threadIdx.x;
  int total = C4 * C2 * 9;
  if (idx >= total) return;
  int tap = idx / (C4 * C2);
  int rem = idx - tap * (C4 * C2);
  int oc = rem / C2;
  int ci = rem - oc * C2;
  Wt[idx] = (__bf16)Wsrc[(oc * C2 + ci) * 9 + tap];
}

__global__ void combine_kernel(const float* __restrict__ hf,
                               const float* __restrict__ hb,
                               float* __restrict__ out, int n) {
  int idx = blockIdx.x * 256 + threadIdx.x;
  if (idx >= n) return;
  out[idx] = (hf[idx] + hb[idx]) * 0.5f;
}

// One block = one (dir d, batch b, row y): all 4C conv channels for that row via
// MFMA implicit GEMM, LSTM gates fused in registers. Wave wv owns channel tiles
// so its 4 gate oc-tiles live in its own accumulators (no cross-wave exchange).
template <int C, int H, int W, int SUB, int NT>
__global__ __launch_bounds__(256)
void convlstm_step_kernel(const float* __restrict__ x_t,     // [B][C][H][W] f32
                          const int* __restrict__ mask_t,    // [B]
                          const __bf16* __restrict__ Wt,     // [2][9][4C][2C] bf16
                          const float* __restrict__ bias_f,  // [4C]
                          const float* __restrict__ bias_b,  // [4C]
                          const float* __restrict__ h_in,    // [2][B][C][H][W] f32
                          float* __restrict__ h_out,         // [2][B][C][H][W] f32
                          float* __restrict__ c_st)          // [2][B][C][H][W] f32
{
  constexpr int B = 8;
  constexpr int C2 = 2 * C, C4 = 4 * C;
  constexpr int COLP = W + 4;        // image x lives at cp = x+2; halo at cp=1, W+2
  constexpr int RS = 3 * COLP + 2;   // RS % 8 == 6 -> B-gather quads spread banks
  constexpr int PLANE = H * W;
  constexpr int CHW = C * PLANE;

  __shared__ __bf16 sIn[C2 * RS];

  const int y = blockIdx.x;
  const int b = blockIdx.y;
  const int d = blockIdx.z;
  const int tid = threadIdx.x;

  const float* hin_b = h_in + (size_t)(d * B + b) * CHW;
  float* hout_b = h_out + (size_t)(d * B + b) * CHW;

  if (mask_t[b] <= 0) {
    // state carry: copy this row of h (c is in-place, untouched)
    constexpr int UN = C * W / 4;
    for (int u = tid; u < UN; u += 256) {
      int c = u / (W / 4);
      int xu = u - c * (W / 4);
      size_t off = (size_t)c * PLANE + (size_t)y * W + xu * 4;
      *reinterpret_cast<float4*>(hout_b + off) =
          *reinterpret_cast<const float4*>(hin_b + off);
    }
    return;
  }

  // ---- stage bf16([x | h]) rows y-1..y+1 into LDS (zero halo / zero OOB) ----
  const float* x_b = x_t + (size_t)b * CHW;
  constexpr int W4 = W / 4;
  constexpr int UNITS = C2 * 3 * W4;
  for (int u = tid; u < UNITS; u += 256) {
    int ci = u / (3 * W4);
    int rem = u - ci * (3 * W4);
    int rr = rem / W4;
    int xu = rem - rr * W4;
    int yy = y + rr - 1;
    unsigned p0 = 0u, p1 = 0u;
    if (yy >= 0 && yy < H) {
      const float* src = (ci < C)
          ? (x_b + (size_t)ci * PLANE + (size_t)yy * W + xu * 4)
          : (hin_b + (size_t)(ci - C) * PLANE + (size_t)yy * W + xu * 4);
      float4 v = *reinterpret_cast<const float4*>(src);
      p0 = pack_bf16x2(v.x, v.y);
      p1 = pack_bf16x2(v.z, v.w);
    }
    int off = ci * RS + rr * COLP + 2 + xu * 4;   // even -> 4B-aligned
    *reinterpret_cast<unsigned int*>(&sIn[off]) = p0;
    *reinterpret_cast<unsigned int*>(&sIn[off + 2]) = p1;
  }
  constexpr int HALO = C2 * 3 * 2;
  for (int u = tid; u < HALO; u += 256) {
    int ci = u / 6;
    int rem = u - ci * 6;
    int rr = rem >> 1;
    int side = rem & 1;
    sIn[ci * RS + rr * COLP + (side ? (W + 2) : 1)] = (__bf16)0.f;
  }
  __syncthreads();

  const int lane = tid & 63;
  const int wv = tid >> 6;
  const int n = lane & 15;   // A: m-index / B: n-index / D: col
  const int q = lane >> 4;   // k quad

  f32x4 acc[4][SUB][NT];
  f32x4 zero = {0.f, 0.f, 0.f, 0.f};
#pragma unroll
  for (int g = 0; g < 4; ++g)
#pragma unroll
    for (int s = 0; s < SUB; ++s)
#pragma unroll
      for (int nt = 0; nt < NT; ++nt) acc[g][s][nt] = zero;

  const __bf16* Wtd = Wt + (size_t)d * (9 * C4 * C2);

  for (int ky = 0; ky < 3; ++ky) {
#pragma unroll
    for (int kx = 0; kx < 3; ++kx) {
      const int tap = ky * 3 + kx;
      const int coff = ky * COLP + kx + 1 + n;   // cp = x + kx + 1, x = nt*16+n
#pragma unroll
      for (int ci0 = 0; ci0 < C2; ci0 += 32) {
        // B fragments: 8 scalar LDS gathers per lane (k = ci0 + q*8 + j)
        bf16x8 bfr[NT];
#pragma unroll
        for (int nt = 0; nt < NT; ++nt) {
#pragma unroll
          for (int j = 0; j < 8; ++j)
            bfr[nt][j] = sIn[(ci0 + q * 8 + j) * RS + coff + nt * 16];
        }
        // A fragments: 16B contiguous from tap-major transposed weights (L2-hot)
        bf16x8 afr[4][SUB];
#pragma unroll
        for (int g = 0; g < 4; ++g) {
#pragma unroll
          for (int s = 0; s < SUB; ++s) {
            int oc = g * C + (wv * SUB + s) * 16 + n;
            afr[g][s] = *reinterpret_cast<const bf16x8*>(
                Wtd + (size_t)(tap * C4 + oc) * C2 + ci0 + q * 8);
          }
        }
#pragma unroll
        for (int g = 0; g < 4; ++g)
#pragma unroll
          for (int s = 0; s < SUB; ++s)
#pragma unroll
            for (int nt = 0; nt < NT; ++nt)
              acc[g][s][nt] = __builtin_amdgcn_mfma_f32_16x16x32_bf16(
                  afr[g][s], bfr[nt], acc[g][s][nt], 0, 0, 0);
      }
    }
  }

  // ---- fused LSTM gate epilogue (D layout: col = n = x, row = q*4+reg = c) ----
  float* c_b = c_st + (size_t)(d * B + b) * CHW;
  const float* bias = (d == 0) ? bias_f : bias_b;
#pragma unroll
  for (int s = 0; s < SUB; ++s) {
#pragma unroll
    for (int r = 0; r < 4; ++r) {
      const int c = (wv * SUB + s) * 16 + q * 4 + r;
      const float bi = bias[0 * C + c];
      const float bff = bias[1 * C + c];
      const float bo = bias[2 * C + c];
      const float bg = bias[3 * C + c];
#pragma unroll
      for (int nt = 0; nt < NT; ++nt) {
        const int x = nt * 16 + n;
        const size_t off = (size_t)c * PLANE + (size_t)y * W + x;
        const float vi = acc[0][s][nt][r] + bi;
        const float vf = acc[1][s][nt][r] + bff;
        const float vo = acc[2][s][nt][r] + bo;
        const float vg = acc[3][s][nt][r] + bg;
        const float cn = sigmoidf_fast(vf) * c_b[off] + sigmoidf_fast(vi) * tanhf_fast(vg);
        c_b[off] = cn;
        hout_b[off] = sigmoidf_fast(vo) * tanhf_fast(cn);
      }
    }
  }
}

extern "C" void kernel_launch(void* const* d_in, const int* in_sizes, int n_in,
                              void* d_out, int out_size, void* d_ws, size_t ws_size,
                              hipStream_t stream) {
  const float* feat0 = (const float*)d_in[0];
  const float* feat1 = (const float*)d_in[1];
  const int* mask = (const int*)d_in[2];
  const float* Wf0 = (const float*)d_in[3];
  const float* bf0 = (const float*)d_in[4];
  const float* Wb0 = (const float*)d_in[5];
  const float* bb0 = (const float*)d_in[6];
  const float* Wf1 = (const float*)d_in[7];
  const float* bf1 = (const float*)d_in[8];
  const float* Wb1 = (const float*)d_in[9];
  const float* bb1 = (const float*)d_in[10];

  const int T = 16;
  const size_t SZ0 = (size_t)8 * 64 * 64 * 64;   // per-(dir,buf) h elements, level 0
  const size_t SZ1 = (size_t)8 * 128 * 32 * 32;  // level 1
  const size_t WT0 = (size_t)9 * 256 * 128;      // per-dir transposed weights
  const size_t WT1 = (size_t)9 * 512 * 256;

  char* p = (char*)d_ws;
  __bf16* Wt0 = (__bf16*)p; p += 2 * WT0 * sizeof(__bf16);
  __bf16* Wt1 = (__bf16*)p; p += 2 * WT1 * sizeof(__bf16);
  float* h0 = (float*)p;    p += 4 * SZ0 * sizeof(float);   // [buf][dir][B][C][H][W]
  float* h1 = (float*)p;    p += 4 * SZ1 * sizeof(float);
  float* c0 = (float*)p;    p += 2 * SZ0 * sizeof(float);   // [dir][B][C][H][W]
  float* c1 = (float*)p;    p += 2 * SZ1 * sizeof(float);

  // zero-init h buf0 (both dirs) and c (ws is re-poisoned 0xAA before every call)
  hipMemsetAsync(h0, 0, 2 * SZ0 * sizeof(float), stream);
  hipMemsetAsync(h1, 0, 2 * SZ1 * sizeof(float), stream);
  hipMemsetAsync(c0, 0, 2 * SZ0 * sizeof(float), stream);
  hipMemsetAsync(c1, 0, 2 * SZ1 * sizeof(float), stream);

  transpose_w_kernel<<<((int)WT0 + 255) / 256, 256, 0, stream>>>(Wf0, Wt0, 256, 128);
  transpose_w_kernel<<<((int)WT0 + 255) / 256, 256, 0, stream>>>(Wb0, Wt0 + WT0, 256, 128);
  transpose_w_kernel<<<((int)WT1 + 255) / 256, 256, 0, stream>>>(Wf1, Wt1, 512, 256);
  transpose_w_kernel<<<((int)WT1 + 255) / 256, 256, 0, stream>>>(Wb1, Wt1 + WT1, 512, 256);

  for (int t = 0; t < T; ++t) {
    const int pi = t & 1, po = 1 - pi;
    convlstm_step_kernel<64, 64, 64, 1, 4><<<dim3(64, 8, 2), 256, 0, stream>>>(
        feat0 + (size_t)t * SZ0, mask + t * 8, Wt0, bf0, bb0,
        h0 + (size_t)pi * 2 * SZ0, h0 + (size_t)po * 2 * SZ0, c0);
    convlstm_step_kernel<128, 32, 32, 2, 2><<<dim3(32, 8, 2), 256, 0, stream>>>(
        feat1 + (size_t)t * SZ1, mask + t * 8, Wt1, bf1, bb1,
        h1 + (size_t)pi * 2 * SZ1, h1 + (size_t)po * 2 * SZ1, c1);
  }

  // T=16 is even -> final states live in buf 0
  float* out = (float*)d_out;
  combine_kernel<<<((int)SZ0 + 255) / 256, 256, 0, stream>>>(h0, h0 + SZ0, out, (int)SZ0);
  combine_kernel<<<((int)SZ1 + 255) / 256, 256, 0, stream>>>(h1, h1 + SZ1, out + SZ0, (int)SZ1);
}